// Round 6
// baseline (1476.915 us; speedup 1.0000x reference)
//
#include <hip/hip_runtime.h>

// ResNetBlock_MoE: B=64,C=64,H=W=56,E=8,TOPK=2. f32 in / f32 out.
// out = sum_k w_k*relu(bn2(conv2(relu(bn1(conv1(x,e)))))+x), plus dense_w.
//
// R5 post-mortem: 928 us, MfmaUtil 3.6 / VALUBusy 11.5 / HBM 4.9% -> latency-
// bound on the 8-per-K-step scattered scalar weight loads (stride 36 B, ~64
// cache lines per wave instruction). R6: stage weights through LDS in 6-step
// chunks (semi-coalesced global reads, conflict-free stride-40 layout), A-frag
// becomes one ds_read_b128. xL/hL share one LDS union buffer to fit 51.5 KB
// (3 blocks/CU). Zero d_ws usage (R1/R2 aborts).

#define BATCH 64
#define CH    64
#define HW_   3136            // 56*56
#define IMG_  (CH*HW_)        // 200704
#define NE    8
#define WSLICE 36864          // per-expert weights: 64*64*9

typedef unsigned short u16;
typedef __attribute__((ext_vector_type(8))) short short8_t;  // 8 bf16 = 4 VGPR
typedef __attribute__((ext_vector_type(4))) float floatx4;

__device__ __forceinline__ u16 f2b(float f) {
    unsigned v; __builtin_memcpy(&v, &f, 4);
    return (u16)((v + 0x7FFFu + ((v >> 16) & 1u)) >> 16);   // RNE
}

// ---------------- gating: GAP -> linear -> top2 softmax -> dense_w (f32) ----
__global__ __launch_bounds__(256) void gate_kernel(
    const float* __restrict__ x, const float* __restrict__ gw,
    const float* __restrict__ gb, float* __restrict__ dw_out)
{
    __shared__ float part[256];
    __shared__ float pooled[CH];
    __shared__ float logits[NE];
    int b = blockIdx.x, tid = threadIdx.x;
    int c = tid >> 2, p = tid & 3;
    const float4* src = (const float4*)(x + (size_t)b*IMG_ + c*HW_ + p*784);
    float s = 0.f;
    for (int i = 0; i < 196; i++) {
        float4 u = src[i];
        s += u.x + u.y + u.z + u.w;
    }
    part[tid] = s;
    __syncthreads();
    if (tid < CH)
        pooled[tid] = (part[4*tid] + part[4*tid+1] + part[4*tid+2] + part[4*tid+3]) * (1.f/3136.f);
    __syncthreads();
    if (tid < NE) {
        float l = gb[tid];
        for (int cc = 0; cc < CH; cc++) l += pooled[cc] * gw[tid*CH + cc];
        logits[tid] = l;
    }
    __syncthreads();
    if (tid == 0) {
        int i1 = 0; float v1 = logits[0];
        for (int e = 1; e < NE; e++) if (logits[e] > v1) { v1 = logits[e]; i1 = e; }
        int i2 = -1; float v2 = -3.4e38f;
        for (int e = 0; e < NE; e++) if (e != i1 && logits[e] > v2) { v2 = logits[e]; i2 = e; }
        float eb = __expf(v2 - v1);
        float wa = 1.f / (1.f + eb), wb = eb / (1.f + eb);
        for (int e = 0; e < NE; e++) dw_out[b*NE + e] = 0.f;
        dw_out[b*NE + i1] = wa;
        dw_out[b*NE + i2] = wb;
    }
}

// ---------------- fused MoE basic block, one (image, 8x8 tile) per block -----
// U: union buffer [144 pos][72] ch-inner bf16 — holds xL (12x12 halo) during
//    conv1, then hL (10x10) during conv2; x re-staged per expert.
// wL: [6 kstep][64 m][40] bf16 A-tiles — stride 80 B: 16B-aligned, bank-free.
__global__ __launch_bounds__(256) void fused_kernel(
    const float* __restrict__ x,
    const float* __restrict__ w1, const float* __restrict__ s1, const float* __restrict__ b1,
    const float* __restrict__ w2, const float* __restrict__ s2, const float* __restrict__ b2,
    const float* __restrict__ dw, float* __restrict__ out)
{
    __shared__ u16 U[144*72];
    __shared__ u16 wL[6*64*40];
    __shared__ int   sE[2];
    __shared__ float sW[2];

    int b    = blockIdx.y;
    int tile = blockIdx.x;              // 0..48
    int ty0 = (tile / 7) * 8, tx0 = (tile % 7) * 8;
    int tid = threadIdx.x;
    int lane = tid & 63, wv = tid >> 6;
    int l15 = lane & 15, q = lane >> 4, qk = q * 8;
    int m = wv * 16 + l15;              // A-operand row for this lane

    if (tid == 0) {
        int e0 = -1, e1 = -1; float wv0 = 0.f, wv1 = 0.f;
        for (int e = 0; e < NE; e++) {
            float w = dw[b*NE + e];
            if (w != 0.f) { if (e0 < 0) { e0 = e; wv0 = w; } else { e1 = e; wv1 = w; } }
        }
        if (e0 < 0) { e0 = 0; wv0 = 0.f; }
        if (e1 < 0) { e1 = e0; wv1 = 0.f; }
        sE[0] = e0; sE[1] = e1; sW[0] = wv0; sW[1] = wv1;
    }

    const float* xb = x + (size_t)b * IMG_;

    // per-lane position indices (k-loop invariant)
    int pIdx1[7];
    #pragma unroll
    for (int f = 0; f < 7; f++) {
        int n = f*16 + l15;             // conv1 GEMM col (0..111; >=100 = pad)
        int hy = n / 10, hx = n - hy*10;
        pIdx1[f] = (hy + 1) * 12 + (hx + 1);
    }
    int pIdx2[4];
    #pragma unroll
    for (int f = 0; f < 4; f++) {
        int n = f*16 + l15;             // conv2 GEMM col (0..63)
        int ty = n >> 3, tx = n & 7;
        pIdx2[f] = (ty + 1) * 10 + (tx + 1);
    }

    // residual, exact f32 from global
    float xres[4][4], oacc[4][4];
    #pragma unroll
    for (int f = 0; f < 4; f++) {
        int n = f*16 + l15;
        int ty = n >> 3, tx = n & 7;
        #pragma unroll
        for (int r = 0; r < 4; r++) {
            int mm = wv*16 + q*4 + r;
            xres[f][r] = xb[mm*HW_ + (ty0 + ty)*56 + (tx0 + tx)];
            oacc[f][r] = 0.f;
        }
    }

    for (int k = 0; k < 2; k++) {
        // ---- stage x tile (zero-padded 12x12 halo, all 64 ch) into U --------
        // (re-staged for k=1 since hL overwrote it; coalesced f32, L2-hot)
        __syncthreads();                 // prior readers of U done
        #pragma unroll
        for (int i = 0; i < 36; i++) {
            int idx = tid + i * 256;    // 0..9215
            int ch  = idx / 144;
            int pos = idx - ch * 144;
            int ry = pos / 12, rx = pos - ry * 12;
            int gy = ty0 - 2 + ry, gx = tx0 - 2 + rx;
            u16 v = 0;
            if ((unsigned)gy < 56u && (unsigned)gx < 56u) v = f2b(xb[ch*HW_ + gy*56 + gx]);
            U[pos*72 + ch] = v;
        }
        __syncthreads();

        int e = sE[k];
        float wk = sW[k];
        const float* we1 = w1 + (size_t)e * WSLICE;
        const float* we2 = w2 + (size_t)e * WSLICE;

        // ---- conv1: h = relu(s1*(W1 (*) x) + b1) over 10x10 region ----------
        floatx4 acc1[7];
        #pragma unroll
        for (int f = 0; f < 7; f++) acc1[f] = (floatx4){0.f,0.f,0.f,0.f};
        for (int c = 0; c < 3; c++) {
            if (c) __syncthreads();      // prior chunk's wL readers done
            // stage wL chunk c: taps {3c,3c+1,3c+2}, K-steps 6c..6c+5
            for (int i = 0; i < 48; i++) {
                int j = tid + i * 256;   // 0..12287
                int mm = j / 192;
                int r  = j - mm * 192;
                int ci = r / 3;
                int tp = r - ci * 3;
                int sl = 2*tp + (ci >> 5);
                int kk = ci & 31;
                wL[(sl*64 + mm)*40 + kk] = f2b(we1[mm*576 + ci*9 + 3*c + tp]);
            }
            __syncthreads();
            #pragma unroll
            for (int sl = 0; sl < 6; sl++) {
                int s = 6*c + sl;
                int tap = s >> 1;
                int dy = tap/3 - 1, dxk = tap - (tap/3)*3 - 1;
                int cib = ((s & 1) << 5) + qk;
                short8_t a = *(const short8_t*)&wL[(sl*64 + m)*40 + qk];
                int doff = dy*12 + dxk;
                #pragma unroll
                for (int f = 0; f < 7; f++) {
                    int p = pIdx1[f] + doff;
                    p = p < 143 ? p : 143;   // clamp pad cols (n>=100)
                    short8_t bf = *(const short8_t*)&U[p*72 + cib];
                    acc1[f] = __builtin_amdgcn_mfma_f32_16x16x32_bf16(a, bf, acc1[f], 0, 0, 0);
                }
            }
        }
        __syncthreads();                 // conv1 U readers done before h write
        {
            float s1v[4], b1v[4];
            #pragma unroll
            for (int r = 0; r < 4; r++) {
                int mm = wv*16 + q*4 + r;
                s1v[r] = s1[e*64 + mm];
                b1v[r] = b1[e*64 + mm];
            }
            #pragma unroll
            for (int f = 0; f < 7; f++) {
                int n = f*16 + l15;
                if (n < 100) {
                    int hy = n / 10, hx = n - hy*10;
                    int gy = ty0 - 1 + hy, gx = tx0 - 1 + hx;
                    bool ins = (unsigned)gy < 56u && (unsigned)gx < 56u;
                    #pragma unroll
                    for (int r = 0; r < 4; r++) {
                        int mm = wv*16 + q*4 + r;
                        float v = ins ? fmaxf(acc1[f][r]*s1v[r] + b1v[r], 0.f) : 0.f;
                        U[n*72 + mm] = f2b(v);   // zero outside image = conv2 pad
                    }
                }
            }
        }
        __syncthreads();                 // hL complete before conv2 reads

        // ---- conv2 + bn2 + residual + relu + weighted combine ---------------
        floatx4 acc2[4];
        #pragma unroll
        for (int f = 0; f < 4; f++) acc2[f] = (floatx4){0.f,0.f,0.f,0.f};
        for (int c = 0; c < 3; c++) {
            __syncthreads();             // prior chunk's wL readers done
            for (int i = 0; i < 48; i++) {
                int j = tid + i * 256;
                int mm = j / 192;
                int r  = j - mm * 192;
                int ci = r / 3;
                int tp = r - ci * 3;
                int sl = 2*tp + (ci >> 5);
                int kk = ci & 31;
                wL[(sl*64 + mm)*40 + kk] = f2b(we2[mm*576 + ci*9 + 3*c + tp]);
            }
            __syncthreads();
            #pragma unroll
            for (int sl = 0; sl < 6; sl++) {
                int s = 6*c + sl;
                int tap = s >> 1;
                int dy = tap/3 - 1, dxk = tap - (tap/3)*3 - 1;
                int cib = ((s & 1) << 5) + qk;
                short8_t a = *(const short8_t*)&wL[(sl*64 + m)*40 + qk];
                int doff = dy*10 + dxk;
                #pragma unroll
                for (int f = 0; f < 4; f++) {
                    int p = pIdx2[f] + doff;          // always in [0,99]
                    short8_t bf = *(const short8_t*)&U[p*72 + cib];
                    acc2[f] = __builtin_amdgcn_mfma_f32_16x16x32_bf16(a, bf, acc2[f], 0, 0, 0);
                }
            }
        }
        {
            float s2v[4], b2v[4];
            #pragma unroll
            for (int r = 0; r < 4; r++) {
                int mm = wv*16 + q*4 + r;
                s2v[r] = s2[e*64 + mm];
                b2v[r] = b2[e*64 + mm];
            }
            #pragma unroll
            for (int f = 0; f < 4; f++)
                #pragma unroll
                for (int r = 0; r < 4; r++) {
                    float yv = acc2[f][r]*s2v[r] + b2v[r];
                    oacc[f][r] += wk * fmaxf(yv + xres[f][r], 0.f);
                }
        }
    }

    float* ob = out + (size_t)b * IMG_;
    #pragma unroll
    for (int f = 0; f < 4; f++) {
        int n = f*16 + l15;
        int ty = n >> 3, tx = n & 7;
        #pragma unroll
        for (int r = 0; r < 4; r++) {
            int mm = wv*16 + q*4 + r;
            ob[mm*HW_ + (ty0 + ty)*56 + (tx0 + tx)] = oacc[f][r];
        }
    }
}

extern "C" void kernel_launch(void* const* d_in, const int* in_sizes, int n_in,
                              void* d_out, int out_size, void* d_ws, size_t ws_size,
                              hipStream_t stream) {
    const float* x   = (const float*)d_in[0];
    const float* gw  = (const float*)d_in[1];
    const float* gb  = (const float*)d_in[2];
    const float* w1  = (const float*)d_in[3];
    const float* s1  = (const float*)d_in[4];
    const float* b1  = (const float*)d_in[5];
    const float* w2  = (const float*)d_in[6];
    const float* s2  = (const float*)d_in[7];
    const float* b2  = (const float*)d_in[8];
    float* out = (float*)d_out;
    float* dw  = out + (size_t)BATCH * IMG_;   // dense_w region of d_out (f32)

    (void)d_ws; (void)ws_size;                 // zero workspace usage

    hipLaunchKernelGGL(gate_kernel, dim3(BATCH), dim3(256), 0, stream, x, gw, gb, dw);
    hipLaunchKernelGGL(fused_kernel, dim3(49, BATCH), dim3(256), 0, stream,
                       x, w1, s1, b1, w2, s2, b2, dw, out);
}

// Round 7
// 452.285 us; speedup vs baseline: 3.2655x; 3.2655x over previous
//
#include <hip/hip_runtime.h>

// ResNetBlock_MoE: B=64,C=64,H=W=56,E=8,TOPK=2. f32 in / f32 out.
// out = sum_k w_k*relu(bn2(conv2(relu(bn1(conv1(x,e)))))+x), plus dense_w.
//
// R6 post-mortem: per-block LDS weight staging kept the same 576 per-thread
// weight ops but added barrier serialization + occupancy loss -> 1395us.
// R7: __device__ STATIC scratch (legal: no hipMalloc, rewritten every call)
// revives the split-kernel design: pack weights ONCE into MFMA A-frag order
// (A-frag = one coalesced 16B load), conv kernels do M64xN64xK576 implicit
// GEMM with fully-coalesced B staging; h round-trips through static g_h.

#define BATCH 64
#define CH    64
#define HW_   3136            // 56*56
#define IMG_  (CH*HW_)        // 200704
#define NE    8
#define JOBS  128
#define PWSZ  36864           // per-expert packed weights: 18*64*32

typedef unsigned short u16;
typedef __attribute__((ext_vector_type(8))) short short8_t;  // 8 bf16 = 4 VGPR
typedef __attribute__((ext_vector_type(4))) float floatx4;

__device__ u16   g_h[(size_t)JOBS * IMG_];   // conv1 output, bf16 [job][c][pos]
__device__ u16   g_pw1[NE * PWSZ];           // packed conv1 weights (bn1_s folded)
__device__ u16   g_pw2[NE * PWSZ];           // packed conv2 weights (bn2_s folded)
__device__ int   g_eid[JOBS];
__device__ float g_wgt[JOBS];

__device__ __forceinline__ u16 f2b(float f) {
    unsigned v; __builtin_memcpy(&v, &f, 4);
    return (u16)((v + 0x7FFFu + ((v >> 16) & 1u)) >> 16);   // RNE
}
__device__ __forceinline__ u16 to_b(float v) { return f2b(v); }
__device__ __forceinline__ u16 to_b(u16 v)   { return v; }

// ---------------- weight pre-pack: fold bn scale, reorder to MFMA A layout ---
// packed[e][s][m][kk] = w[e][m][ci][tap] * bn_s[e][m], ci=(s&1)*32+kk, tap=s>>1
__global__ __launch_bounds__(256) void pack_kernel(
    const float* __restrict__ w1, const float* __restrict__ s1,
    const float* __restrict__ w2, const float* __restrict__ s2)
{
    int idx = blockIdx.x * 256 + threadIdx.x;        // < 2*8*36864 = 589824
    int conv = idx / 294912;
    int i2 = idx - conv * 294912;
    int e = i2 / PWSZ;   int r = i2 - e * PWSZ;
    int s = r / 2048;    r -= s * 2048;
    int m = r / 32;      int kk = r - m * 32;
    int tap = s >> 1;
    int ci = ((s & 1) << 5) | kk;
    const float* w  = conv ? w2 : w1;
    const float* sc = conv ? s2 : s1;
    float v = w[((e*64 + m)*64 + ci)*9 + tap] * sc[e*64 + m];
    (conv ? g_pw2 : g_pw1)[i2] = f2b(v);
}

// ---------------- gating: GAP -> linear -> top2 softmax ---------------------
__global__ __launch_bounds__(256) void gate_kernel(
    const float* __restrict__ x, const float* __restrict__ gw,
    const float* __restrict__ gb, float* __restrict__ dw_out)
{
    __shared__ float part[256];
    __shared__ float pooled[CH];
    __shared__ float logits[NE];
    int b = blockIdx.x, tid = threadIdx.x;
    int c = tid >> 2, p = tid & 3;
    const float4* src = (const float4*)(x + (size_t)b*IMG_ + c*HW_ + p*784);
    float s = 0.f;
    for (int i = 0; i < 196; i++) {
        float4 u = src[i];
        s += u.x + u.y + u.z + u.w;
    }
    part[tid] = s;
    __syncthreads();
    if (tid < CH)
        pooled[tid] = (part[4*tid] + part[4*tid+1] + part[4*tid+2] + part[4*tid+3]) * (1.f/3136.f);
    __syncthreads();
    if (tid < NE) {
        float l = gb[tid];
        for (int cc = 0; cc < CH; cc++) l += pooled[cc] * gw[tid*CH + cc];
        logits[tid] = l;
    }
    __syncthreads();
    if (tid == 0) {
        int i1 = 0; float v1 = logits[0];
        for (int e = 1; e < NE; e++) if (logits[e] > v1) { v1 = logits[e]; i1 = e; }
        int i2 = -1; float v2 = -3.4e38f;
        for (int e = 0; e < NE; e++) if (e != i1 && logits[e] > v2) { v2 = logits[e]; i2 = e; }
        float eb = __expf(v2 - v1);
        float wa = 1.f / (1.f + eb), wb = eb / (1.f + eb);
        for (int e = 0; e < NE; e++) dw_out[b*NE + e] = 0.f;
        dw_out[b*NE + i1] = wa;
        dw_out[b*NE + i2] = wb;
        g_eid[2*b] = i1; g_eid[2*b+1] = i2;
        g_wgt[2*b] = wa; g_wgt[2*b+1] = wb;
    }
}

// ---------------- implicit-GEMM 3x3 conv inner loop (M=64 x N=64 tile) ------
// in: [64][3136] image (f32 x or bf16 h); wp: packed [18][64][32] bf16;
// Bs: LDS im2col [n=64][kk 32+8pad] — stride 40 u16 = 2-way banks only.
template<typename T>
__device__ __forceinline__ void conv_gemm(
    const T* __restrict__ in, const u16* __restrict__ wp,
    int N0, u16 (*Bs)[40], floatx4 acc[4])
{
    int tid = threadIdx.x;
    int lane = tid & 63;
    int wv = tid >> 6;
    int l15 = lane & 15;
    int qk = ((lane >> 4) & 3) * 8;
    int gn = N0 + lane;
    int y = gn / 56;
    int xc = gn - y * 56;
    int kkb = wv * 8;                    // this wave stages kk in [kkb,kkb+8)
    int mrow = wv * 16 + l15;            // A-frag row for this lane
    const T* inb = in + gn;
    for (int s = 0; s < 18; s++) {
        int tap = s >> 1;
        int dy = tap / 3 - 1, dxk = tap - (tap/3)*3 - 1;
        bool vld = ((unsigned)(y + dy) < 56u) && ((unsigned)(xc + dxk) < 56u);
        const T* sp = inb + (((s & 1) << 5) + kkb) * HW_ + dy * 56 + dxk;
        union { u16 u[8]; short8_t v8; } tmp;
        #pragma unroll
        for (int i = 0; i < 8; i++) tmp.u[i] = vld ? to_b(sp[i * HW_]) : (u16)0;
        short8_t a = *(const short8_t*)(wp + (s*64 + mrow)*32 + qk);  // coalesced 16B, L2-hot
        __syncthreads();                                  // prior readers done
        *(short8_t*)&Bs[lane][kkb] = tmp.v8;              // one ds_write_b128
        __syncthreads();
        #pragma unroll
        for (int f = 0; f < 4; f++) {
            short8_t bfr = *(const short8_t*)&Bs[f*16 + l15][qk];
            acc[f] = __builtin_amdgcn_mfma_f32_16x16x32_bf16(a, bfr, acc[f], 0, 0, 0);
        }
    }
}

// ---------------- conv1 + bn1 + relu -> g_h (bf16) --------------------------
__global__ __launch_bounds__(256) void conv1_kernel(
    const float* __restrict__ x, const float* __restrict__ b1)
{
    __shared__ u16 Bs[64][40];
    int tile = blockIdx.x;          // 0..48
    int job  = blockIdx.y;          // 0..127
    int b = job >> 1;
    int e = g_eid[job];
    floatx4 acc[4] = {};
    conv_gemm<float>(x + (size_t)b*IMG_, g_pw1 + e*PWSZ, tile*64, Bs, acc);
    int tid = threadIdx.x, lane = tid & 63, wv = tid >> 6;
    int q = (lane >> 4) & 3, l15 = lane & 15;
    u16* hb = g_h + (size_t)job*IMG_ + tile*64 + l15;
    #pragma unroll
    for (int f = 0; f < 4; f++)
        #pragma unroll
        for (int r = 0; r < 4; r++) {
            int m = wv*16 + q*4 + r;
            float v = acc[f][r] + b1[e*64 + m];
            hb[m*HW_ + f*16] = f2b(fmaxf(v, 0.f));
        }
}

// ---------------- conv2 + bn2 + residual + relu + 2-slot combine ------------
__global__ __launch_bounds__(256) void conv2_kernel(
    const float* __restrict__ x, const float* __restrict__ b2,
    float* __restrict__ out)
{
    __shared__ u16 Bs[64][40];
    int tile = blockIdx.x, b = blockIdx.y;
    int tid = threadIdx.x, lane = tid & 63, wv = tid >> 6;
    int q = (lane >> 4) & 3, l15 = lane & 15;
    const float* xb = x + (size_t)b*IMG_ + tile*64 + l15;
    float xv[4][4], oacc[4][4];
    #pragma unroll
    for (int f = 0; f < 4; f++)
        #pragma unroll
        for (int r = 0; r < 4; r++) {
            xv[f][r] = xb[(wv*16 + q*4 + r)*HW_ + f*16];
            oacc[f][r] = 0.f;
        }
    for (int k = 0; k < 2; k++) {
        int job = 2*b + k;
        int e = g_eid[job];
        float wk = g_wgt[job];
        floatx4 acc[4] = {};
        conv_gemm<u16>(g_h + (size_t)job*IMG_, g_pw2 + e*PWSZ, tile*64, Bs, acc);
        #pragma unroll
        for (int f = 0; f < 4; f++)
            #pragma unroll
            for (int r = 0; r < 4; r++) {
                int m = wv*16 + q*4 + r;
                float yv = acc[f][r] + b2[e*64 + m];
                oacc[f][r] += wk * fmaxf(yv + xv[f][r], 0.f);
            }
    }
    float* ob = out + (size_t)b*IMG_ + tile*64 + l15;
    #pragma unroll
    for (int f = 0; f < 4; f++)
        #pragma unroll
        for (int r = 0; r < 4; r++)
            ob[(wv*16 + q*4 + r)*HW_ + f*16] = oacc[f][r];
}

extern "C" void kernel_launch(void* const* d_in, const int* in_sizes, int n_in,
                              void* d_out, int out_size, void* d_ws, size_t ws_size,
                              hipStream_t stream) {
    const float* x   = (const float*)d_in[0];
    const float* gw  = (const float*)d_in[1];
    const float* gb  = (const float*)d_in[2];
    const float* w1  = (const float*)d_in[3];
    const float* s1  = (const float*)d_in[4];
    const float* b1  = (const float*)d_in[5];
    const float* w2  = (const float*)d_in[6];
    const float* s2  = (const float*)d_in[7];
    const float* b2  = (const float*)d_in[8];
    float* out = (float*)d_out;
    float* dw  = out + (size_t)BATCH * IMG_;   // dense_w region of d_out (f32)

    (void)d_ws; (void)ws_size;                 // zero d_ws usage (R1/R2 aborts)

    hipLaunchKernelGGL(pack_kernel, dim3(2304), dim3(256), 0, stream, w1, s1, w2, s2);
    hipLaunchKernelGGL(gate_kernel, dim3(BATCH), dim3(256), 0, stream, x, gw, gb, dw);
    hipLaunchKernelGGL(conv1_kernel, dim3(49, JOBS), dim3(256), 0, stream, x, b1);
    hipLaunchKernelGGL(conv2_kernel, dim3(49, BATCH), dim3(256), 0, stream, x, b2, out);
}

// Round 8
// 447.230 us; speedup vs baseline: 3.3024x; 1.0113x over previous
//
#include <hip/hip_runtime.h>

// ResNetBlock_MoE: B=64,C=64,H=W=56,E=8,TOPK=2. f32 in / f32 out.
// out = sum_k w_k*relu(bn2(conv2(relu(bn1(conv1(x,e)))))+x), plus dense_w.
//
// R7 post-mortem: 452us. conv1 FETCH=480MB (x f32 re-read 9 taps x 3 rows,
// L2 half-miss), MfmaUtil 5.4% (2 barriers + 5 ds_b128 per K-step).
// R8: (1) x pre-converted to bf16 g_xb once -> per-image footprint 401KB,
// fits XCD L2 across the whole tap sweep; (2) barrier-free K-loop: waves own
// disjoint position groups, B-fragment loaded straight to registers (no LDS,
// no __syncthreads in conv kernels), A-fragment one coalesced 16B load from
// pre-packed weights. Static __device__ scratch (d_ws unusable per R1/R2).

#define BATCH 64
#define CH    64
#define HW_   3136            // 56*56
#define IMG_  (CH*HW_)        // 200704
#define NE    8
#define JOBS  128
#define PWSZ  36864           // per-expert packed weights: 18*64*32

typedef unsigned short u16;
typedef __attribute__((ext_vector_type(8))) short short8_t;  // 8 bf16 = 4 VGPR
typedef __attribute__((ext_vector_type(4))) float floatx4;

__device__ u16   g_xb[(size_t)BATCH * IMG_];  // x as bf16 [b][c][pos]
__device__ u16   g_h[(size_t)JOBS * IMG_];    // conv1 out, bf16 [job][c][pos]
__device__ u16   g_pw1[NE * PWSZ];            // packed conv1 w (bn1_s folded)
__device__ u16   g_pw2[NE * PWSZ];            // packed conv2 w (bn2_s folded)
__device__ int   g_eid[JOBS];
__device__ float g_wgt[JOBS];

__device__ __forceinline__ u16 f2b(float f) {
    unsigned v; __builtin_memcpy(&v, &f, 4);
    return (u16)((v + 0x7FFFu + ((v >> 16) & 1u)) >> 16);   // RNE
}

// ---------------- weight pre-pack: fold bn scale, reorder to MFMA A layout ---
// packed[e][s][m][kk] = w[e][m][ci][tap] * bn_s[e][m], ci=(s&1)*32+kk, tap=s>>1
__global__ __launch_bounds__(256) void pack_kernel(
    const float* __restrict__ w1, const float* __restrict__ s1,
    const float* __restrict__ w2, const float* __restrict__ s2)
{
    int idx = blockIdx.x * 256 + threadIdx.x;        // < 2*8*36864 = 589824
    int conv = idx / 294912;
    int i2 = idx - conv * 294912;
    int e = i2 / PWSZ;   int r = i2 - e * PWSZ;
    int s = r / 2048;    r -= s * 2048;
    int m = r / 32;      int kk = r - m * 32;
    int tap = s >> 1;
    int ci = ((s & 1) << 5) | kk;
    const float* w  = conv ? w2 : w1;
    const float* sc = conv ? s2 : s1;
    float v = w[((e*64 + m)*64 + ci)*9 + tap] * sc[e*64 + m];
    (conv ? g_pw2 : g_pw1)[i2] = f2b(v);
}

// ---------------- x -> bf16 convert (once per launch) -----------------------
__global__ __launch_bounds__(256) void xconv_kernel(const float* __restrict__ x)
{
    size_t i = ((size_t)blockIdx.x * 256 + threadIdx.x) * 8;   // grid covers exactly
    float4 a = *(const float4*)(x + i);
    float4 b = *(const float4*)(x + i + 4);
    union { u16 u[8]; short8_t v; } t;
    t.u[0]=f2b(a.x); t.u[1]=f2b(a.y); t.u[2]=f2b(a.z); t.u[3]=f2b(a.w);
    t.u[4]=f2b(b.x); t.u[5]=f2b(b.y); t.u[6]=f2b(b.z); t.u[7]=f2b(b.w);
    *(short8_t*)(g_xb + i) = t.v;
}

// ---------------- gating: GAP -> linear -> top2 softmax ---------------------
__global__ __launch_bounds__(256) void gate_kernel(
    const float* __restrict__ x, const float* __restrict__ gw,
    const float* __restrict__ gb, float* __restrict__ dw_out)
{
    __shared__ float part[256];
    __shared__ float pooled[CH];
    __shared__ float logits[NE];
    int b = blockIdx.x, tid = threadIdx.x;
    int c = tid >> 2, p = tid & 3;
    const float4* src = (const float4*)(x + (size_t)b*IMG_ + c*HW_ + p*784);
    float s = 0.f;
    for (int i = 0; i < 196; i++) {
        float4 u = src[i];
        s += u.x + u.y + u.z + u.w;
    }
    part[tid] = s;
    __syncthreads();
    if (tid < CH)
        pooled[tid] = (part[4*tid] + part[4*tid+1] + part[4*tid+2] + part[4*tid+3]) * (1.f/3136.f);
    __syncthreads();
    if (tid < NE) {
        float l = gb[tid];
        for (int cc = 0; cc < CH; cc++) l += pooled[cc] * gw[tid*CH + cc];
        logits[tid] = l;
    }
    __syncthreads();
    if (tid == 0) {
        int i1 = 0; float v1 = logits[0];
        for (int e = 1; e < NE; e++) if (logits[e] > v1) { v1 = logits[e]; i1 = e; }
        int i2 = -1; float v2 = -3.4e38f;
        for (int e = 0; e < NE; e++) if (e != i1 && logits[e] > v2) { v2 = logits[e]; i2 = e; }
        float eb = __expf(v2 - v1);
        float wa = 1.f / (1.f + eb), wb = eb / (1.f + eb);
        for (int e = 0; e < NE; e++) dw_out[b*NE + e] = 0.f;
        dw_out[b*NE + i1] = wa;
        dw_out[b*NE + i2] = wb;
        g_eid[2*b] = i1; g_eid[2*b+1] = i2;
        g_wgt[2*b] = wa; g_wgt[2*b+1] = wb;
    }
}

// ---------------- barrier-free implicit-GEMM 3x3 conv inner loop ------------
// Wave wv owns positions N0+wv*16..+15 (B-frag cols); computes all 64 m-rows
// via 4 m-block MFMAs. B-frag loaded per-lane from global (bf16, L2-hot);
// A-frag one coalesced 16B load from packed weights. No LDS, no barriers.
__device__ __forceinline__ void conv_gemm_reg(
    const u16* __restrict__ in, const u16* __restrict__ wp,
    int N0, floatx4 acc[4])
{
    int lane = threadIdx.x & 63;
    int wv = threadIdx.x >> 6;
    int l15 = lane & 15, q = lane >> 4, qk = q * 8;
    int gn = N0 + wv*16 + l15;          // this lane's output position (B col)
    int y = gn / 56, xc = gn - y * 56;
    const u16* inb = in + gn;
    for (int s = 0; s < 18; s++) {
        int tap = s >> 1;
        int dy = tap / 3 - 1, dxk = tap - (tap/3)*3 - 1;
        bool vld = ((unsigned)(y + dy) < 56u) && ((unsigned)(xc + dxk) < 56u);
        const u16* sp = inb + (((s & 1) << 5) + qk) * HW_ + dy * 56 + dxk;
        union { u16 u[8]; short8_t v8; } B;
        #pragma unroll
        for (int j = 0; j < 8; j++) B.u[j] = vld ? sp[j * HW_] : (u16)0;
        const u16* ap = wp + (s*64 + l15)*32 + qk;
        #pragma unroll
        for (int mb = 0; mb < 4; mb++) {
            short8_t a = *(const short8_t*)(ap + mb*512);   // (mb*16)*32
            acc[mb] = __builtin_amdgcn_mfma_f32_16x16x32_bf16(a, B.v8, acc[mb], 0, 0, 0);
        }
    }
}

// ---------------- conv1 + bn1 + relu -> g_h (bf16) --------------------------
__global__ __launch_bounds__(256) void conv1_kernel(const float* __restrict__ b1)
{
    int tile = blockIdx.x;          // 0..48
    int job  = blockIdx.y;          // 0..127
    int b = job >> 1;
    int e = g_eid[job];
    floatx4 acc[4] = {};
    conv_gemm_reg(g_xb + (size_t)b*IMG_, g_pw1 + e*PWSZ, tile*64, acc);
    int lane = threadIdx.x & 63, wv = threadIdx.x >> 6;
    int l15 = lane & 15, q = lane >> 4;
    int gn = tile*64 + wv*16 + l15;
    u16* hb = g_h + (size_t)job*IMG_ + gn;
    #pragma unroll
    for (int mb = 0; mb < 4; mb++)
        #pragma unroll
        for (int r = 0; r < 4; r++) {
            int m = mb*16 + q*4 + r;
            float v = acc[mb][r] + b1[e*64 + m];
            hb[m*HW_] = f2b(fmaxf(v, 0.f));
        }
}

// ---------------- conv2 + bn2 + residual + relu + 2-slot combine ------------
__global__ __launch_bounds__(256) void conv2_kernel(
    const float* __restrict__ x, const float* __restrict__ b2,
    float* __restrict__ out)
{
    int tile = blockIdx.x, b = blockIdx.y;
    int lane = threadIdx.x & 63, wv = threadIdx.x >> 6;
    int l15 = lane & 15, q = lane >> 4;
    int gn = tile*64 + wv*16 + l15;
    const float* xb = x + (size_t)b*IMG_ + gn;
    float xres[4][4], oacc[4][4];
    #pragma unroll
    for (int mb = 0; mb < 4; mb++)
        #pragma unroll
        for (int r = 0; r < 4; r++) {
            xres[mb][r] = xb[(mb*16 + q*4 + r)*HW_];
            oacc[mb][r] = 0.f;
        }
    for (int k = 0; k < 2; k++) {
        int job = 2*b + k;
        int e = g_eid[job];
        float wk = g_wgt[job];
        floatx4 acc[4] = {};
        conv_gemm_reg(g_h + (size_t)job*IMG_, g_pw2 + e*PWSZ, tile*64, acc);
        #pragma unroll
        for (int mb = 0; mb < 4; mb++)
            #pragma unroll
            for (int r = 0; r < 4; r++) {
                int m = mb*16 + q*4 + r;
                float yv = acc[mb][r] + b2[e*64 + m];
                oacc[mb][r] += wk * fmaxf(yv + xres[mb][r], 0.f);
            }
    }
    float* ob = out + (size_t)b*IMG_ + gn;
    #pragma unroll
    for (int mb = 0; mb < 4; mb++)
        #pragma unroll
        for (int r = 0; r < 4; r++)
            ob[(mb*16 + q*4 + r)*HW_] = oacc[mb][r];
}

extern "C" void kernel_launch(void* const* d_in, const int* in_sizes, int n_in,
                              void* d_out, int out_size, void* d_ws, size_t ws_size,
                              hipStream_t stream) {
    const float* x   = (const float*)d_in[0];
    const float* gw  = (const float*)d_in[1];
    const float* gb  = (const float*)d_in[2];
    const float* w1  = (const float*)d_in[3];
    const float* s1  = (const float*)d_in[4];
    const float* b1  = (const float*)d_in[5];
    const float* w2  = (const float*)d_in[6];
    const float* s2  = (const float*)d_in[7];
    const float* b2  = (const float*)d_in[8];
    float* out = (float*)d_out;
    float* dw  = out + (size_t)BATCH * IMG_;   // dense_w region of d_out (f32)

    (void)d_ws; (void)ws_size;                 // zero d_ws usage (R1/R2 aborts)

    hipLaunchKernelGGL(pack_kernel, dim3(2304), dim3(256), 0, stream, w1, s1, w2, s2);
    hipLaunchKernelGGL(xconv_kernel, dim3(6272), dim3(256), 0, stream, x);
    hipLaunchKernelGGL(gate_kernel, dim3(BATCH), dim3(256), 0, stream, x, gw, gb, dw);
    hipLaunchKernelGGL(conv1_kernel, dim3(49, JOBS), dim3(256), 0, stream, b1);
    hipLaunchKernelGGL(conv2_kernel, dim3(49, BATCH), dim3(256), 0, stream, x, b2, out);
}